// Round 2
// 1559.652 us; speedup vs baseline: 2.0575x; 2.0575x over previous
//
#include <hip/hip_runtime.h>
#include <hip/hip_bf16.h>

// Problem dims: V=32000, E=H=256, L=2, B=32, S=64, S_ENC=64, 2H=512, 3H=768

typedef _Float16 h2v __attribute__((ext_vector_type(2)));
typedef _Float16 f16x8 __attribute__((ext_vector_type(8)));
typedef float f32x4 __attribute__((ext_vector_type(4)));

__device__ inline float sigmf(float x) { return 1.f / (1.f + __expf(-x)); }
__device__ inline float tanhfast(float x) { return 2.f / (1.f + __expf(-2.f * x)) - 1.f; }

// agent-scope fences; __hip_atomic_fence is missing on this ROCm build
__device__ inline void fence_rel_agent() {
#if __has_builtin(__builtin_amdgcn_fence)
  __builtin_amdgcn_fence(__ATOMIC_RELEASE, "agent");
#else
  __threadfence();
#endif
}
__device__ inline void fence_acq_agent() {
#if __has_builtin(__builtin_amdgcn_fence)
  __builtin_amdgcn_fence(__ATOMIC_ACQUIRE, "agent");
#else
  __threadfence();
#endif
}

__device__ inline float dot2acc(unsigned a, unsigned b, float c) {
#if __has_builtin(__builtin_amdgcn_fdot2)
  return __builtin_amdgcn_fdot2(__builtin_bit_cast(h2v, a), __builtin_bit_cast(h2v, b), c, false);
#else
  h2v av = __builtin_bit_cast(h2v, a), bv = __builtin_bit_cast(h2v, b);
  return c + (float)av.x * (float)bv.x + (float)av.y * (float)bv.y;
#endif
}

__device__ inline float dotf16(const _Float16* __restrict__ w, const _Float16* h, int n8) {
  const uint4* wp = (const uint4*)w;
  const uint4* hp = (const uint4*)h;
  float acc = 0.f;
#pragma unroll 4
  for (int i = 0; i < n8; i++) {
    uint4 a = wp[i];
    uint4 b = hp[i];
    acc = dot2acc(a.x, b.x, acc);
    acc = dot2acc(a.y, b.y, acc);
    acc = dot2acc(a.z, b.z, acc);
    acc = dot2acc(a.w, b.w, acc);
  }
  return acc;
}

// ---------------- K0: f32 -> f16 convert ----------------
__global__ void k_cvt(const float* __restrict__ s, _Float16* __restrict__ d, int n) {
  int i = blockIdx.x * blockDim.x + threadIdx.x;
  int stride = gridDim.x * blockDim.x;
  for (; i < n; i += stride) d[i] = (_Float16)s[i];
}

// ---------------- K1: gi0[t,b,:] = relu(emb[tok]) @ Wih0^T + bih0 ----------------
__global__ __launch_bounds__(256) void k_gi0(const int* __restrict__ ow,
                                             const float* __restrict__ emb,
                                             const _Float16* __restrict__ Wih0f,
                                             const float* __restrict__ b_ih,
                                             float* __restrict__ gi0,
                                             int* __restrict__ sy) {
  // zero the k_rec2 grid-barrier state (runs before k_rec2 on the stream)
  if (blockIdx.x == 0 && threadIdx.x < 2) sy[threadIdx.x * 32] = 0;
  __shared__ __align__(16) _Float16 x[256];
  int m = blockIdx.x;            // m = t*32 + b
  int b = m & 31, t = m >> 5;
  int tid = threadIdx.x;
  int tok = ow[b * 65 + t];      // teacher forcing uses output_words[:, :-1]
  x[tid] = (_Float16)fmaxf(emb[(size_t)tok * 256 + tid], 0.f);
  __syncthreads();
#pragma unroll
  for (int p = 0; p < 3; p++) {
    int j = tid + p * 256;
    gi0[(size_t)m * 768 + j] = dotf16(Wih0f + (size_t)j * 256, x, 32) + b_ih[j];
  }
}

// ---------------- K2: cooperative GRU recurrence ----------------
// 24 blocks x 384 threads. Blocks 0..7: layer 0 (32 dims each).
// Blocks 8..23: layer 1 (16 dims each). Weights live in registers for the
// whole kernel (one 16-row x 256-col f16 tile per wave = 16 VGPRs/lane).
// Pipelined: iteration i computes h0(i) (layer0) and h1(i-1) (layer1), so
// ONE device-scope barrier per iteration. h vectors exchanged via ping-pong
// f16 buffers in global memory with agent-scope release/acquire fences
// (handles cross-XCD L2 non-coherence). f32 hidden state kept block-local
// in LDS -> numerics match previous kernel.
#define NBLK 24

__global__ __launch_bounds__(384) void k_rec2(const float* __restrict__ ehid,
                                              const _Float16* __restrict__ Whh0f,
                                              const _Float16* __restrict__ Wih1f,
                                              const _Float16* __restrict__ Whh1f,
                                              const float* __restrict__ b_ih,
                                              const float* __restrict__ b_hh,
                                              const float* __restrict__ gi0,
                                              _Float16* H1,      // no restrict: aliasing keeps reloads honest
                                              _Float16* h0b,     // [2][32][256] f16 ping-pong
                                              _Float16* h1b,     // [2][32][256] f16 ping-pong
                                              int* sy) {         // [0]=arrival counter, [32]=generation
  __shared__ float gsm[96][33];   // staged gate pre-activations [local_row][batch]
  __shared__ float hloc[32][33];  // block-local f32 hidden slice [dim][batch]
  const int g = blockIdx.x;
  const int tid = threadIdx.x;
  const int w = tid >> 6, lane = tid & 63;
  const int lm = lane & 15, lq = lane >> 4;
  const bool L0 = (g < 8);
  const int j = g - 8;
  int bk = 0;

  // ---- weight fragments into registers (persist across all 64 steps) ----
  int row0;
  const _Float16* Wsel;
  if (L0)         { row0 = (w >> 1) * 256 + g * 32 + (w & 1) * 16; Wsel = Whh0f; }
  else if (w < 3) { row0 = w * 256 + j * 16;                       Wsel = Wih1f; }
  else            { row0 = (w - 3) * 256 + j * 16;                 Wsel = Whh1f; }
  f16x8 bf[8];
  {
    const _Float16* Wp = Wsel + (size_t)(row0 + lm) * 256 + lq * 8;
#pragma unroll
    for (int c = 0; c < 8; c++) bf[c] = *(const f16x8*)(Wp + c * 32);
  }

  // ---- init f32 local hidden state + publish f16 copy into slot 1 ----
  // ehid layout (4,32,256): h0 = dl0+dl2, h1 = dl1+dl3
  if (L0) {
    for (int it = tid; it < 1024; it += 384) {
      int dd = it & 31, b = it >> 5, d = g * 32 + dd;
      float v = ehid[(size_t)b * 256 + d] + ehid[(size_t)(64 + b) * 256 + d];
      hloc[dd][b] = v;
      h0b[(size_t)(32 + b) * 256 + d] = (_Float16)v;
    }
  } else {
    for (int it = tid; it < 512; it += 384) {
      int dd = it & 15, b = it >> 4, d = j * 16 + dd;
      float v = ehid[(size_t)(32 + b) * 256 + d] + ehid[(size_t)(96 + b) * 256 + d];
      hloc[dd][b] = v;
      h1b[(size_t)(32 + b) * 256 + d] = (_Float16)v;
    }
  }

  // ---- monotonic-counter grid barrier (24 co-resident blocks) ----
  auto gridbar = [&]() {
    asm volatile("" ::: "memory");
    __syncthreads();
    if (tid == 0) {
      fence_rel_agent();
      int v = __hip_atomic_fetch_add(sy, 1, __ATOMIC_RELAXED, __HIP_MEMORY_SCOPE_AGENT);
      int tgt = bk * NBLK + NBLK;
      if (v == tgt - 1) {
        __hip_atomic_store(sy + 32, tgt, __ATOMIC_RELEASE, __HIP_MEMORY_SCOPE_AGENT);
      } else {
        int guard = 0;
        while (__hip_atomic_load(sy + 32, __ATOMIC_RELAXED, __HIP_MEMORY_SCOPE_AGENT) < tgt) {
          __builtin_amdgcn_s_sleep(4);
          if (++guard > (1 << 22)) break;  // safety valve: wrong-answer beats hang
        }
      }
      fence_acq_agent();
    }
    bk++;
    __syncthreads();
    asm volatile("" ::: "memory");
  };

  gridbar();  // make init writes visible everywhere

  for (int i = 0; i <= 64; i++) {
    const bool active = L0 ? (i < 64) : (i >= 1);
    if (active) {
      // A operand: layer0 + ga-waves read h0(i-1); gb-waves read h1(i-2)
      const _Float16* Ab = (L0 || w < 3) ? (h0b + (((i + 1) & 1) << 13))
                                         : (h1b + ((i & 1) << 13));
      f32x4 acc[2] = {};
#pragma unroll
      for (int c = 0; c < 8; c++) {
#pragma unroll
        for (int mt = 0; mt < 2; mt++) {
          f16x8 a = *(const f16x8*)(Ab + (size_t)((mt * 16 + lm) * 256 + c * 32 + lq * 8));
          acc[mt] = __builtin_amdgcn_mfma_f32_16x16x32_f16(a, bf[c], acc[mt], 0, 0, 0);
        }
      }
      // stage to LDS: row = w*16 + lm (neuron), col = mt*16 + lq*4 + r (batch)
#pragma unroll
      for (int mt = 0; mt < 2; mt++)
#pragma unroll
        for (int r = 0; r < 4; r++)
          gsm[w * 16 + lm][mt * 16 + lq * 4 + r] = acc[mt][r];
      __syncthreads();

      if (L0) {
        // h0(i) for dims [g*32, g*32+32); gsm rows: r=0..31, z=32..63, n=64..95
        const float* gi = gi0 + (size_t)i * 32 * 768;
        _Float16* hw = h0b + ((i & 1) << 13);
        for (int it = tid; it < 1024; it += 384) {
          int dd = it & 31, b = it >> 5, d = g * 32 + dd;
          const float* gib = gi + (size_t)b * 768 + d;
          float r = sigmf(gib[0] + gsm[dd][b] + b_hh[d]);
          float z = sigmf(gib[256] + gsm[32 + dd][b] + b_hh[256 + d]);
          float n = tanhfast(gib[512] + r * (gsm[64 + dd][b] + b_hh[512 + d]));
          float h = (1.f - z) * n + z * hloc[dd][b];
          hloc[dd][b] = h;
          hw[(size_t)b * 256 + d] = (_Float16)h;
        }
      } else {
        // h1(i-1) for dims [j*16, j*16+16)
        // gsm rows: ga_r=0..15, ga_z=16..31, ga_n=32..47, gb_r=48..63, gb_z=64..79, gb_n=80..95
        const int t = i - 1;
        _Float16* hw = h1b + (((i + 1) & 1) << 13);
        for (int it = tid; it < 512; it += 384) {
          int dd = it & 15, b = it >> 4, d = j * 16 + dd;
          float gar = gsm[dd][b]      + b_ih[768 + d];
          float gaz = gsm[16 + dd][b] + b_ih[1024 + d];
          float gan = gsm[32 + dd][b] + b_ih[1280 + d];
          float gbr = gsm[48 + dd][b] + b_hh[768 + d];
          float gbz = gsm[64 + dd][b] + b_hh[1024 + d];
          float gbn = gsm[80 + dd][b] + b_hh[1280 + d];
          float r = sigmf(gar + gbr);
          float z = sigmf(gaz + gbz);
          float n = tanhfast(gan + r * gbn);
          float h = (1.f - z) * n + z * hloc[dd][b];
          hloc[dd][b] = h;
          _Float16 hf = (_Float16)h;
          hw[(size_t)b * 256 + d] = hf;
          H1[(size_t)(t * 32 + b) * 256 + d] = hf;
        }
      }
    }
    if (i < 64) gridbar();
  }
}

// ---------------- K3: attention + Ww projection per (t,b) ----------------
__global__ __launch_bounds__(256) void k_attn(const _Float16* __restrict__ H1,
                                              const _Float16* __restrict__ Waf,
                                              const float* __restrict__ ba,
                                              const _Float16* __restrict__ ench,
                                              const _Float16* __restrict__ Wwf,
                                              const float* __restrict__ bw,
                                              _Float16* __restrict__ Omat) {
  __shared__ __align__(16) _Float16 cat[768];   // [0:256)=h1, [256:768)=ctx
  __shared__ __align__(16) _Float16 qh[512];
  __shared__ float sc[64], wgt[64];
  int m = blockIdx.x, tid = threadIdx.x;
  int b = m & 31;

  cat[tid] = H1[(size_t)m * 256 + tid];
  __syncthreads();
#pragma unroll
  for (int p = 0; p < 2; p++) {
    int j = tid + p * 256;
    qh[j] = (_Float16)(dotf16(Waf + (size_t)j * 256, cat, 32) + ba[j]);
  }
  __syncthreads();
  if (tid < 64) sc[tid] = dotf16(ench + (size_t)(b * 64 + tid) * 512, qh, 64);
  __syncthreads();
  if (tid < 64) {  // softmax over 64 within wave 0
    float v = sc[tid], mx = v;
    for (int o = 32; o; o >>= 1) mx = fmaxf(mx, __shfl_xor(mx, o, 64));
    float e = __expf(v - mx), sm = e;
    for (int o = 32; o; o >>= 1) sm += __shfl_xor(sm, o, 64);
    wgt[tid] = e / sm;
  }
  __syncthreads();
#pragma unroll
  for (int p = 0; p < 2; p++) {
    int d = tid + p * 256;
    float acc = 0.f;
    const _Float16* ep = ench + (size_t)b * 64 * 512 + d;
#pragma unroll 8
    for (int s = 0; s < 64; s++) acc += wgt[s] * (float)ep[(size_t)s * 512];
    cat[256 + d] = (_Float16)acc;
  }
  __syncthreads();
#pragma unroll
  for (int p = 0; p < 3; p++) {
    int j = tid + p * 256;
    float o = dotf16(Wwf + (size_t)j * 768, cat, 96) + bw[j];
    Omat[(size_t)m * 768 + j] = (_Float16)fmaxf(o, 0.f);
  }
}

// ---------------- K4: logits = O @ Wo^T + bo, MFMA f16, permuted (b,t) store ----------------
__global__ __launch_bounds__(256) void k_gemm(const _Float16* __restrict__ O,
                                              const _Float16* __restrict__ Wo,
                                              const float* __restrict__ bo,
                                              float* __restrict__ out) {
  int idx = blockIdx.x;
  int mb = idx & 15;        // 16 m-blocks of 128 (M=2048)
  int nb = idx >> 4;        // 250 n-blocks of 128 (N=32000)
  int wave = threadIdx.x >> 6;
  int lane = threadIdx.x & 63;
  int m0 = mb * 128 + (wave >> 1) * 64;
  int n0 = nb * 128 + (wave & 1) * 64;
  int lm = lane & 15, lq = lane >> 4;

  f32x4 acc[4][4] = {};

  for (int kc = 0; kc < 768; kc += 32) {
    f16x8 a[4], bfr[4];
#pragma unroll
    for (int i = 0; i < 4; i++) {
      a[i]   = *(const f16x8*)(O  + (size_t)(m0 + 16 * i + lm) * 768 + kc + lq * 8);
      bfr[i] = *(const f16x8*)(Wo + (size_t)(n0 + 16 * i + lm) * 768 + kc + lq * 8);
    }
#pragma unroll
    for (int i = 0; i < 4; i++)
#pragma unroll
      for (int j = 0; j < 4; j++)
        acc[i][j] = __builtin_amdgcn_mfma_f32_16x16x32_f16(a[i], bfr[j], acc[i][j], 0, 0, 0);
  }

#pragma unroll
  for (int j = 0; j < 4; j++) {
    int n = n0 + 16 * j + lm;
    float bias = bo[n];
#pragma unroll
    for (int i = 0; i < 4; i++) {
#pragma unroll
      for (int r = 0; r < 4; r++) {
        int m = m0 + 16 * i + lq * 4 + r;   // m = t*32 + b
        int b = m & 31, t = m >> 5;
        out[(size_t)(b * 64 + t) * 32000 + n] = acc[i][j][r] + bias;
      }
    }
  }
}

extern "C" void kernel_launch(void* const* d_in, const int* in_sizes, int n_in,
                              void* d_out, int out_size, void* d_ws, size_t ws_size,
                              hipStream_t stream) {
  const float* enc  = (const float*)d_in[0];
  const float* ehid = (const float*)d_in[1];
  const int*   ow   = (const int*)d_in[2];
  const float* emb  = (const float*)d_in[3];
  const float* W_ih = (const float*)d_in[4];
  const float* W_hh = (const float*)d_in[5];
  const float* b_ih = (const float*)d_in[6];
  const float* b_hh = (const float*)d_in[7];
  const float* Wa   = (const float*)d_in[8];
  const float* ba   = (const float*)d_in[9];
  const float* Ww   = (const float*)d_in[10];
  const float* bw   = (const float*)d_in[11];
  const float* Wo   = (const float*)d_in[12];
  const float* bo   = (const float*)d_in[13];
  float* out = (float*)d_out;

  char* w = (char*)d_ws;
  _Float16* Wih0f = (_Float16*)(w + 0);
  _Float16* Whh0f = (_Float16*)(w + 393216);
  _Float16* Wih1f = (_Float16*)(w + 786432);
  _Float16* Whh1f = (_Float16*)(w + 1179648);
  _Float16* Waf   = (_Float16*)(w + 1572864);
  _Float16* Wwf   = (_Float16*)(w + 1835008);
  _Float16* ench  = (_Float16*)(w + 3014656);
  float*    gi0   = (float*)   (w + 5111808);
  _Float16* H1    = (_Float16*)(w + 11403264);
  _Float16* Omat  = (_Float16*)(w + 12451840);
  _Float16* Wof   = (_Float16*)(w + 15597568);
  _Float16* h0b   = (_Float16*)(w + 64749568);  // 2*32*256 f16 = 32 KB
  _Float16* h1b   = (_Float16*)(w + 64782336);  // 2*32*256 f16 = 32 KB
  int*      sy    = (int*)     (w + 64815104);  // barrier counter/generation
  // total ws use: ~64.82 MB

  k_cvt<<<256,  256, 0, stream>>>(W_ih,           Wih0f, 196608);
  k_cvt<<<256,  256, 0, stream>>>(W_hh,           Whh0f, 196608);
  k_cvt<<<256,  256, 0, stream>>>(W_ih + 196608,  Wih1f, 196608);
  k_cvt<<<256,  256, 0, stream>>>(W_hh + 196608,  Whh1f, 196608);
  k_cvt<<<256,  256, 0, stream>>>(Wa,             Waf,   131072);
  k_cvt<<<512,  256, 0, stream>>>(Ww,             Wwf,   589824);
  k_cvt<<<512,  256, 0, stream>>>(enc,            ench,  1048576);
  k_cvt<<<2048, 256, 0, stream>>>(Wo,             Wof,   24576000);

  k_gi0 <<<2048, 256, 0, stream>>>(ow, emb, Wih0f, b_ih, gi0, sy);
  k_rec2<<<NBLK, 384, 0, stream>>>(ehid, Whh0f, Wih1f, Whh1f, b_ih, b_hh, gi0,
                                   H1, h0b, h1b, sy);
  k_attn<<<2048, 256, 0, stream>>>(H1, Waf, ba, ench, Wwf, bw, Omat);
  k_gemm<<<4000, 256, 0, stream>>>(Omat, Wof, bo, out);
}